// Round 2
// baseline (365.354 us; speedup 1.0000x reference)
//
#include <hip/hip_runtime.h>

typedef _Float16 f16x8 __attribute__((ext_vector_type(8)));
typedef float f32x4 __attribute__((ext_vector_type(4)));

#define D_IN 768
#define D_H  256
#define SEQ  2048

// ---------------- K0: W1 [768][256] f32 -> W1T [256][768] f16 (transposed) ---
__global__ __launch_bounds__(256) void k0_w1t(const float* __restrict__ W1,
                                              _Float16* __restrict__ W1T) {
  __shared__ float tl[64][65];
  const int kb = blockIdx.x, nb = blockIdx.y, t = threadIdx.x;
#pragma unroll
  for (int rep = 0; rep < 16; ++rep) {
    const int row = rep * 4 + (t >> 6), col = t & 63;
    tl[row][col] = W1[(size_t)(kb * 64 + row) * D_H + nb * 64 + col];
  }
  __syncthreads();
#pragma unroll
  for (int rep = 0; rep < 16; ++rep) {
    const int n = rep * 4 + (t >> 6), k = t & 63;
    W1T[(size_t)(nb * 64 + n) * D_IN + kb * 64 + k] = (_Float16)tl[k][n];
  }
}

// ---------------- KF: fused logits + local softmax + local pooling -----------
// 2048 blocks (64 batch x 32 rowblocks of 64 rows) x 512 threads.
// X tile stays LDS-resident (fp16) -> X read from HBM exactly once.
// Outputs per block: Ppart[bid][4][768] fp16 (unnorm. exp-weighted X sums),
//                    stats[bid][c] = {local max, local sumexp}.
__global__ __launch_bounds__(512, 1) void kf_fused(const float* __restrict__ X,
    const _Float16* __restrict__ W1T, const float* __restrict__ b1,
    const float* __restrict__ C, _Float16* __restrict__ Ppart,
    float* __restrict__ stats) {
  __shared__ _Float16 Xl[64][776];   // +8 pad: row stride 1552B -> bank +4/row
  __shared__ _Float16 Bl[256][72];
  __shared__ float red[64][4];
  __shared__ float ms4[4], Ss4[4];
  const int t = threadIdx.x;
  const int bid = blockIdx.x;
  const size_t M0 = (size_t)bid * 64;

  const int xrow = t >> 3, xkc = t & 7;        // X stage: 64 rows x 8 k-chunks
  const int bcolS = t >> 1, bh = t & 1;        // B stage: 256 cols x 2 halves
  const float*    Ag = X + (M0 + xrow) * D_IN + xkc * 8;
  const _Float16* Bg = W1T + (size_t)bcolS * D_IN + bh * 32;

  f32x4 acc[2][4];
#pragma unroll
  for (int i = 0; i < 2; ++i)
#pragma unroll
    for (int j = 0; j < 4; ++j) acc[i][j] = f32x4{0.f, 0.f, 0.f, 0.f};

  float4 a0 = *(const float4*)(Ag);
  float4 a1 = *(const float4*)(Ag + 4);
  uint4 bq0 = *(const uint4*)(Bg);
  uint4 bq1 = *(const uint4*)(Bg + 8);
  uint4 bq2 = *(const uint4*)(Bg + 16);
  uint4 bq3 = *(const uint4*)(Bg + 24);

  const int lane = t & 63, wv = t >> 6;
  const int wm = wv >> 2, wn = wv & 3;         // 2 m-waves x 4 n-waves
  const int l15 = lane & 15, kg = lane >> 4;

  for (int kt = 0; kt < 12; ++kt) {
    f16x8 ha;
    ha[0] = (_Float16)a0.x; ha[1] = (_Float16)a0.y; ha[2] = (_Float16)a0.z; ha[3] = (_Float16)a0.w;
    ha[4] = (_Float16)a1.x; ha[5] = (_Float16)a1.y; ha[6] = (_Float16)a1.z; ha[7] = (_Float16)a1.w;
    *(f16x8*)&Xl[xrow][kt * 64 + xkc * 8] = ha;   // builds resident X tile
    *(uint4*)&Bl[bcolS][bh * 32]      = bq0;
    *(uint4*)&Bl[bcolS][bh * 32 + 8]  = bq1;
    *(uint4*)&Bl[bcolS][bh * 32 + 16] = bq2;
    *(uint4*)&Bl[bcolS][bh * 32 + 24] = bq3;
    __syncthreads();
    if (kt < 11) {  // register prefetch of next k-chunk (overlaps MFMA)
      const float* An = Ag + (kt + 1) * 64;
      a0 = *(const float4*)(An);
      a1 = *(const float4*)(An + 4);
      const _Float16* Bn = Bg + (kt + 1) * 64;
      bq0 = *(const uint4*)(Bn);
      bq1 = *(const uint4*)(Bn + 8);
      bq2 = *(const uint4*)(Bn + 16);
      bq3 = *(const uint4*)(Bn + 24);
    }
#pragma unroll
    for (int st = 0; st < 2; ++st) {
      f16x8 af[2], bf[4];
#pragma unroll
      for (int i = 0; i < 2; ++i)
        af[i] = *(const f16x8*)&Xl[wm * 32 + i * 16 + l15][kt * 64 + st * 32 + kg * 8];
#pragma unroll
      for (int j = 0; j < 4; ++j)
        bf[j] = *(const f16x8*)&Bl[wn * 64 + j * 16 + l15][st * 32 + kg * 8];
#pragma unroll
      for (int j = 0; j < 4; ++j)
#pragma unroll
        for (int i = 0; i < 2; ++i)
          acc[i][j] = __builtin_amdgcn_mfma_f32_16x16x32_f16(af[i], bf[j], acc[i][j], 0, 0, 0);
    }
    __syncthreads();
  }

  // ---- epilogue 1: logits = tanh(z) @ C, reduced into red[64][4] ----
  if (t < 256) ((float*)red)[t] = 0.f;
  __syncthreads();

  float part[2][4][4];
#pragma unroll
  for (int i = 0; i < 2; ++i)
#pragma unroll
    for (int r = 0; r < 4; ++r)
#pragma unroll
      for (int c = 0; c < 4; ++c) part[i][r][c] = 0.f;

#pragma unroll
  for (int j = 0; j < 4; ++j) {
    const int col = wn * 64 + j * 16 + l15;
    const float4 c4 = *(const float4*)(C + col * 4);
    const float bv = b1[col];
#pragma unroll
    for (int i = 0; i < 2; ++i)
#pragma unroll
      for (int r = 0; r < 4; ++r) {
        float z = acc[i][j][r] + bv;
        z = fminf(fmaxf(z, -15.f), 15.f);
        const float e = __expf(2.f * z);
        const float h = (e - 1.f) / (e + 1.f);   // tanh(z)
        part[i][r][0] += h * c4.x;
        part[i][r][1] += h * c4.y;
        part[i][r][2] += h * c4.z;
        part[i][r][3] += h * c4.w;
      }
  }
#pragma unroll
  for (int off = 1; off < 16; off <<= 1) {
#pragma unroll
    for (int i = 0; i < 2; ++i)
#pragma unroll
      for (int r = 0; r < 4; ++r)
#pragma unroll
        for (int c = 0; c < 4; ++c)
          part[i][r][c] += __shfl_xor(part[i][r][c], off, 64);
  }
  if (l15 == 0) {
#pragma unroll
    for (int i = 0; i < 2; ++i)
#pragma unroll
      for (int r = 0; r < 4; ++r)
#pragma unroll
        for (int c = 0; c < 4; ++c)
          atomicAdd(&red[wm * 32 + i * 16 + kg * 4 + r][c], part[i][r][c]);
  }
  __syncthreads();

  // ---- epilogue 2: block-local softmax stats, red <- exp(l - m_local) ----
  if (t < 4) {
    float m = red[0][t];
#pragma unroll 8
    for (int r = 1; r < 64; ++r) m = fmaxf(m, red[r][t]);
    ms4[t] = m;
  }
  __syncthreads();
  if (t < 256) {
    const int r = t >> 2, c = t & 3;
    red[r][c] = __expf(red[r][c] - ms4[c]);
  }
  __syncthreads();
  if (t < 4) {
    float s = 0.f;
#pragma unroll 8
    for (int r = 0; r < 64; ++r) s += red[r][t];
    Ss4[t] = s;
  }
  __syncthreads();
  if (t < 8) stats[(size_t)bid * 8 + t] = (t & 1) ? Ss4[t >> 1] : ms4[t >> 1];

  // ---- epilogue 3: partial pooling P[c][d] = sum_r e[r][c] * Xl[r][d] ----
  const int pc = t >> 7, pch = t & 127;
  if (pch < 96) {
    float a8[8] = {0.f, 0.f, 0.f, 0.f, 0.f, 0.f, 0.f, 0.f};
    for (int r = 0; r < 64; ++r) {
      const float w = red[r][pc];
      const f16x8 x8 = *(const f16x8*)&Xl[r][pch * 8];
#pragma unroll
      for (int k = 0; k < 8; ++k) a8[k] += w * (float)x8[k];
    }
    f16x8 o;
#pragma unroll
    for (int k = 0; k < 8; ++k) o[k] = (_Float16)a8[k];
    *(f16x8*)&Ppart[(size_t)bid * 3072 + pc * 768 + pch * 8] = o;
  }
}

// ---------------- KC: combine 32 block-partials per batch -> pooled ----------
__global__ __launch_bounds__(256) void kc_combine(const _Float16* __restrict__ Ppart,
    const float* __restrict__ stats, float* __restrict__ pooled) {
  const int b = blockIdx.x, t = threadIdx.x;
  __shared__ float sm[32][8];
  __shared__ float Mc[4], Dc[4], fw[32][4];
  sm[t >> 3][t & 7] = stats[((size_t)b * 32 + (t >> 3)) * 8 + (t & 7)];
  __syncthreads();
  if (t < 4) {
    float m = sm[0][t * 2];
#pragma unroll
    for (int blk = 1; blk < 32; ++blk) m = fmaxf(m, sm[blk][t * 2]);
    Mc[t] = m;
  }
  __syncthreads();
  if (t < 128) {
    const int blk = t >> 2, c = t & 3;
    fw[blk][c] = __expf(sm[blk][c * 2] - Mc[c]);
  }
  __syncthreads();
  if (t < 4) {
    float s = 0.f;
#pragma unroll
    for (int blk = 0; blk < 32; ++blk) s += fw[blk][t] * sm[blk][t * 2 + 1];
    Dc[t] = 1.f / s;
  }
  __syncthreads();
#pragma unroll
  for (int c = 0; c < 4; ++c) {
#pragma unroll
    for (int rep = 0; rep < 3; ++rep) {
      const int d = rep * 256 + t;
      float acc = 0.f;
#pragma unroll 4
      for (int blk = 0; blk < 32; ++blk)
        acc += fw[blk][c] * (float)Ppart[((size_t)(b * 32 + blk)) * 3072 + c * 768 + d];
      pooled[(size_t)b * 3072 + c * 768 + d] = fmaxf(acc * Dc[c], 0.f);
    }
  }
}

// ---------------- K4: partial[kc][b][j] = pooled(k-slice) @ W2(k-slice) ------
__global__ __launch_bounds__(256) void k4_partial(const float* __restrict__ pooled,
                                                  const float* __restrict__ W2,
                                                  float* __restrict__ partial) {
  const int jc = blockIdx.x, kc = blockIdx.y, t = threadIdx.x;
  __shared__ float plds[64 * 192];
  __shared__ float sum2[64][64];
  for (int idx = t; idx < 64 * 192; idx += 256) {
    const int b = idx / 192, k = idx - b * 192;
    plds[idx] = pooled[(size_t)b * 3072 + kc * 192 + k];
  }
  __syncthreads();
  const int j = t & 63, kp = t >> 6;
  float acc[64];
#pragma unroll
  for (int b = 0; b < 64; ++b) acc[b] = 0.f;
  const float* W2p = W2 + (size_t)(kc * 192 + kp * 48) * D_IN + jc * 64 + j;
  const float* pb = plds + kp * 48;
  for (int ki = 0; ki < 48; ki += 4) {
    const float w0 = W2p[(size_t)(ki + 0) * D_IN];
    const float w1 = W2p[(size_t)(ki + 1) * D_IN];
    const float w2 = W2p[(size_t)(ki + 2) * D_IN];
    const float w3 = W2p[(size_t)(ki + 3) * D_IN];
#pragma unroll
    for (int b = 0; b < 64; ++b) {
      const float4 p4 = *(const float4*)(pb + b * 192 + ki);
      acc[b] += p4.x * w0 + p4.y * w1 + p4.z * w2 + p4.w * w3;
    }
  }
#pragma unroll
  for (int p = 0; p < 4; ++p) {
    if (kp == p) {
      if (p == 0) {
#pragma unroll
        for (int b = 0; b < 64; ++b) sum2[b][j] = acc[b];
      } else {
#pragma unroll
        for (int b = 0; b < 64; ++b) sum2[b][j] += acc[b];
      }
    }
    __syncthreads();
  }
  for (int idx = t; idx < 4096; idx += 256) {
    const int b = idx >> 6, jj = idx & 63;
    partial[(size_t)kc * 49152 + (size_t)b * D_IN + jc * 64 + jj] = sum2[b][jj];
  }
}

// ---------------- K5: out = sum(partials) + b2 -------------------------------
__global__ __launch_bounds__(256) void k5_final(const float* __restrict__ partial,
                                                const float* __restrict__ b2,
                                                float* __restrict__ out) {
  const int o = blockIdx.x * 256 + threadIdx.x;
  float v = b2[o % D_IN];
#pragma unroll
  for (int p = 0; p < 16; ++p) v += partial[(size_t)p * 49152 + o];
  out[o] = v;
}

extern "C" void kernel_launch(void* const* d_in, const int* in_sizes, int n_in,
                              void* d_out, int out_size, void* d_ws, size_t ws_size,
                              hipStream_t stream) {
  const float* X  = (const float*)d_in[0];
  const float* W1 = (const float*)d_in[1];
  const float* b1 = (const float*)d_in[2];
  const float* C  = (const float*)d_in[3];
  const float* W2 = (const float*)d_in[4];
  const float* b2 = (const float*)d_in[5];
  float* out = (float*)d_out;
  char* ws = (char*)d_ws;
  _Float16* W1T   = (_Float16*)ws;              //       0 .. 393,216
  float* pooled   = (float*)(ws + 393216);      // 393,216 .. 1,179,648
  float* stats    = (float*)(ws + 1179648);     // 1,179,648 .. 1,245,184
  _Float16* Ppart = (_Float16*)(ws + 1245184);  // 1,245,184 .. 13,828,096
  float* partial  = (float*)(ws + 1245184);     // aliases Ppart (used after KC)

  k0_w1t    <<<dim3(12, 4), 256, 0, stream>>>(W1, W1T);
  kf_fused  <<<2048,        512, 0, stream>>>(X, W1T, b1, C, Ppart, stats);
  kc_combine<<<64,          256, 0, stream>>>(Ppart, stats, pooled);
  k4_partial<<<dim3(12,16), 256, 0, stream>>>(pooled, W2, partial);
  k5_final  <<<192,         256, 0, stream>>>(partial, b2, out);
}

// Round 3
// 334.367 us; speedup vs baseline: 1.0927x; 1.0927x over previous
//
#include <hip/hip_runtime.h>

typedef _Float16 f16x8 __attribute__((ext_vector_type(8)));
typedef float f32x4 __attribute__((ext_vector_type(4)));

#define D_IN 768
#define D_H  256
#define SEQ  2048

// ---------------- K0: W1 [768][256] f32 -> W1T [256][768] f16 (transposed) ---
__global__ __launch_bounds__(256) void k0_w1t(const float* __restrict__ W1,
                                              _Float16* __restrict__ W1T) {
  __shared__ float tl[64][65];
  const int kb = blockIdx.x, nb = blockIdx.y, t = threadIdx.x;
#pragma unroll
  for (int rep = 0; rep < 16; ++rep) {
    const int row = rep * 4 + (t >> 6), col = t & 63;
    tl[row][col] = W1[(size_t)(kb * 64 + row) * D_H + nb * 64 + col];
  }
  __syncthreads();
#pragma unroll
  for (int rep = 0; rep < 16; ++rep) {
    const int n = rep * 4 + (t >> 6), k = t & 63;
    W1T[(size_t)(nb * 64 + n) * D_IN + kb * 64 + k] = (_Float16)tl[k][n];
  }
}

// ---------------- KF: fused logits + local softmax + local pooling -----------
// 2048 blocks x 512 threads, 1 block/CU (137KB LDS). Raw s_barrier (no vmcnt
// drain) + depth-2 register prefetch: loads for kt+2 stay in flight across
// both barriers of kt and all of kt+1 -> k-loop is X-bandwidth-bound.
__global__ __launch_bounds__(512, 1) void kf_fused(const float* __restrict__ X,
    const _Float16* __restrict__ W1T, const float* __restrict__ b1,
    const float* __restrict__ C, _Float16* __restrict__ Ppart,
    float* __restrict__ stats) {
  __shared__ _Float16 Xl[64][776];
  __shared__ _Float16 Bl[256][72];
  __shared__ float red[64][4];
  const int t = threadIdx.x;
  const int bid = blockIdx.x;
  const size_t M0 = (size_t)bid * 64;

  const int xrow = t >> 3, xkc = t & 7;        // X stage: 64 rows x 8 k-chunks
  const int bcolS = t >> 1, bh = t & 1;        // B stage: 256 cols x 2 halves
  const float*    Ag = X + (M0 + xrow) * D_IN + xkc * 8;
  const _Float16* Bg = W1T + (size_t)bcolS * D_IN + bh * 32;

  f32x4 acc[2][4];
#pragma unroll
  for (int i = 0; i < 2; ++i)
#pragma unroll
    for (int j = 0; j < 4; ++j) acc[i][j] = f32x4{0.f, 0.f, 0.f, 0.f};

  const int lane = t & 63, wv = t >> 6;
  const int wm = wv >> 2, wn = wv & 3;         // 2 m-waves x 4 n-waves
  const int l15 = lane & 15, kg = lane >> 4;

  // two named prefetch register sets (static indexing only — rule #20)
  float4 a0_0, a1_0; uint4 b0_0, b1_0, b2_0, b3_0;   // even kt
  float4 a0_1, a1_1; uint4 b0_1, b1_1, b2_1, b3_1;   // odd kt

  a0_0 = *(const float4*)(Ag);
  a1_0 = *(const float4*)(Ag + 4);
  b0_0 = *(const uint4*)(Bg);
  b1_0 = *(const uint4*)(Bg + 8);
  b2_0 = *(const uint4*)(Bg + 16);
  b3_0 = *(const uint4*)(Bg + 24);
  a0_1 = *(const float4*)(Ag + 64);
  a1_1 = *(const float4*)(Ag + 68);
  b0_1 = *(const uint4*)(Bg + 64);
  b1_1 = *(const uint4*)(Bg + 72);
  b2_1 = *(const uint4*)(Bg + 80);
  b3_1 = *(const uint4*)(Bg + 88);

  auto body = [&](int kt, float4& A0, float4& A1,
                  uint4& B0, uint4& B1, uint4& B2, uint4& B3) {
    // stage current chunk to LDS (compiler inserts counted vmcnt for A0..B3)
    f16x8 ha;
    ha[0] = (_Float16)A0.x; ha[1] = (_Float16)A0.y; ha[2] = (_Float16)A0.z; ha[3] = (_Float16)A0.w;
    ha[4] = (_Float16)A1.x; ha[5] = (_Float16)A1.y; ha[6] = (_Float16)A1.z; ha[7] = (_Float16)A1.w;
    *(f16x8*)&Xl[xrow][kt * 64 + xkc * 8] = ha;   // builds resident X tile
    *(uint4*)&Bl[bcolS][bh * 32]      = B0;
    *(uint4*)&Bl[bcolS][bh * 32 + 8]  = B1;
    *(uint4*)&Bl[bcolS][bh * 32 + 16] = B2;
    *(uint4*)&Bl[bcolS][bh * 32 + 24] = B3;
    if (kt < 10) {  // refill this set for kt+2; stays in flight across barriers
      const float* An = Ag + (kt + 2) * 64;
      A0 = *(const float4*)(An);
      A1 = *(const float4*)(An + 4);
      const _Float16* Bn = Bg + (kt + 2) * 64;
      B0 = *(const uint4*)(Bn);
      B1 = *(const uint4*)(Bn + 8);
      B2 = *(const uint4*)(Bn + 16);
      B3 = *(const uint4*)(Bn + 24);
    }
    asm volatile("s_waitcnt lgkmcnt(0)" ::: "memory");  // LDS writes visible
    __builtin_amdgcn_sched_barrier(0);
    asm volatile("s_barrier" ::: "memory");             // NO vmcnt drain
#pragma unroll
    for (int st = 0; st < 2; ++st) {
      f16x8 af[2], bf[4];
#pragma unroll
      for (int i = 0; i < 2; ++i)
        af[i] = *(const f16x8*)&Xl[wm * 32 + i * 16 + l15][kt * 64 + st * 32 + kg * 8];
#pragma unroll
      for (int j = 0; j < 4; ++j)
        bf[j] = *(const f16x8*)&Bl[wn * 64 + j * 16 + l15][st * 32 + kg * 8];
#pragma unroll
      for (int j = 0; j < 4; ++j)
#pragma unroll
        for (int i = 0; i < 2; ++i)
          acc[i][j] = __builtin_amdgcn_mfma_f32_16x16x32_f16(af[i], bf[j], acc[i][j], 0, 0, 0);
    }
    __builtin_amdgcn_sched_barrier(0);
    asm volatile("s_barrier" ::: "memory");   // protect Bl overwrite next kt
  };

#pragma unroll
  for (int kp = 0; kp < 6; ++kp) {
    body(2 * kp,     a0_0, a1_0, b0_0, b1_0, b2_0, b3_0);
    body(2 * kp + 1, a0_1, a1_1, b0_1, b1_1, b2_1, b3_1);
  }

  // ---- epilogue 1: logits = tanh(z) @ C, reduced into red[64][4] ----
  if (t < 256) ((float*)red)[t] = 0.f;
  __syncthreads();

  float part[2][4][4];
#pragma unroll
  for (int i = 0; i < 2; ++i)
#pragma unroll
    for (int r = 0; r < 4; ++r)
#pragma unroll
      for (int c = 0; c < 4; ++c) part[i][r][c] = 0.f;

#pragma unroll
  for (int j = 0; j < 4; ++j) {
    const int col = wn * 64 + j * 16 + l15;
    const float4 c4 = *(const float4*)(C + col * 4);
    const float bv = b1[col];
#pragma unroll
    for (int i = 0; i < 2; ++i)
#pragma unroll
      for (int r = 0; r < 4; ++r) {
        float z = acc[i][j][r] + bv;
        z = fminf(fmaxf(z, -15.f), 15.f);
        const float e = __expf(2.f * z);
        const float h = (e - 1.f) / (e + 1.f);   // tanh(z)
        part[i][r][0] += h * c4.x;
        part[i][r][1] += h * c4.y;
        part[i][r][2] += h * c4.z;
        part[i][r][3] += h * c4.w;
      }
  }
#pragma unroll
  for (int off = 1; off < 16; off <<= 1) {
#pragma unroll
    for (int i = 0; i < 2; ++i)
#pragma unroll
      for (int r = 0; r < 4; ++r)
#pragma unroll
        for (int c = 0; c < 4; ++c)
          part[i][r][c] += __shfl_xor(part[i][r][c], off, 64);
  }
  if (l15 == 0) {
#pragma unroll
    for (int i = 0; i < 2; ++i)
#pragma unroll
      for (int r = 0; r < 4; ++r)
#pragma unroll
        for (int c = 0; c < 4; ++c)
          atomicAdd(&red[wm * 32 + i * 16 + kg * 4 + r][c], part[i][r][c]);
  }
  __syncthreads();

  // ---- epilogue 2: wave-parallel block-local softmax stats ----
  // wave c (c=t>>6 < 4) owns context c; lane r = row. red <- exp(l - m_local).
  if (t < 256) {
    const int c = t >> 6, r = t & 63;
    const float v = red[r][c];
    float m = v;
#pragma unroll
    for (int off = 1; off < 64; off <<= 1) m = fmaxf(m, __shfl_xor(m, off, 64));
    const float e = __expf(v - m);
    red[r][c] = e;
    float s = e;
#pragma unroll
    for (int off = 1; off < 64; off <<= 1) s += __shfl_xor(s, off, 64);
    if (r < 2) stats[(size_t)bid * 8 + c * 2 + r] = (r == 0) ? m : s;
  }
  __syncthreads();

  // ---- epilogue 3: partial pooling P[c][d] = sum_r e[r][c] * Xl[r][d] ----
  const int pc = t >> 7, pch = t & 127;
  if (pch < 96) {
    float a8[8] = {0.f, 0.f, 0.f, 0.f, 0.f, 0.f, 0.f, 0.f};
    for (int r = 0; r < 64; ++r) {
      const float w = red[r][pc];
      const f16x8 x8 = *(const f16x8*)&Xl[r][pch * 8];
#pragma unroll
      for (int k = 0; k < 8; ++k) a8[k] += w * (float)x8[k];
    }
    f16x8 o;
#pragma unroll
    for (int k = 0; k < 8; ++k) o[k] = (_Float16)a8[k];
    *(f16x8*)&Ppart[(size_t)bid * 3072 + pc * 768 + pch * 8] = o;
  }
}

// ---------------- KC: combine 32 block-partials per batch -> pooled ----------
__global__ __launch_bounds__(256) void kc_combine(const _Float16* __restrict__ Ppart,
    const float* __restrict__ stats, float* __restrict__ pooled) {
  const int b = blockIdx.x, t = threadIdx.x;
  __shared__ float sm[32][8];
  __shared__ float Mc[4], Dc[4], fw[32][4];
  sm[t >> 3][t & 7] = stats[((size_t)b * 32 + (t >> 3)) * 8 + (t & 7)];
  __syncthreads();
  if (t < 4) {
    float m = sm[0][t * 2];
#pragma unroll
    for (int blk = 1; blk < 32; ++blk) m = fmaxf(m, sm[blk][t * 2]);
    Mc[t] = m;
  }
  __syncthreads();
  if (t < 128) {
    const int blk = t >> 2, c = t & 3;
    fw[blk][c] = __expf(sm[blk][c * 2] - Mc[c]);
  }
  __syncthreads();
  if (t < 4) {
    float s = 0.f;
#pragma unroll
    for (int blk = 0; blk < 32; ++blk) s += fw[blk][t] * sm[blk][t * 2 + 1];
    Dc[t] = 1.f / s;
  }
  __syncthreads();
#pragma unroll
  for (int c = 0; c < 4; ++c) {
#pragma unroll
    for (int rep = 0; rep < 3; ++rep) {
      const int d = rep * 256 + t;
      float acc = 0.f;
#pragma unroll 4
      for (int blk = 0; blk < 32; ++blk)
        acc += fw[blk][c] * (float)Ppart[((size_t)(b * 32 + blk)) * 3072 + c * 768 + d];
      pooled[(size_t)b * 3072 + c * 768 + d] = fmaxf(acc * Dc[c], 0.f);
    }
  }
}

// ---------------- K4: partial[kc][b][j] = pooled(k-slice) @ W2(k-slice) ------
__global__ __launch_bounds__(256) void k4_partial(const float* __restrict__ pooled,
                                                  const float* __restrict__ W2,
                                                  float* __restrict__ partial) {
  const int jc = blockIdx.x, kc = blockIdx.y, t = threadIdx.x;
  __shared__ float plds[64 * 192];
  __shared__ float sum2[64][64];
  for (int idx = t; idx < 64 * 192; idx += 256) {
    const int b = idx / 192, k = idx - b * 192;
    plds[idx] = pooled[(size_t)b * 3072 + kc * 192 + k];
  }
  __syncthreads();
  const int j = t & 63, kp = t >> 6;
  float acc[64];
#pragma unroll
  for (int b = 0; b < 64; ++b) acc[b] = 0.f;
  const float* W2p = W2 + (size_t)(kc * 192 + kp * 48) * D_IN + jc * 64 + j;
  const float* pb = plds + kp * 48;
  for (int ki = 0; ki < 48; ki += 4) {
    const float w0 = W2p[(size_t)(ki + 0) * D_IN];
    const float w1 = W2p[(size_t)(ki + 1) * D_IN];
    const float w2 = W2p[(size_t)(ki + 2) * D_IN];
    const float w3 = W2p[(size_t)(ki + 3) * D_IN];
#pragma unroll
    for (int b = 0; b < 64; ++b) {
      const float4 p4 = *(const float4*)(pb + b * 192 + ki);
      acc[b] += p4.x * w0 + p4.y * w1 + p4.z * w2 + p4.w * w3;
    }
  }
#pragma unroll
  for (int p = 0; p < 4; ++p) {
    if (kp == p) {
      if (p == 0) {
#pragma unroll
        for (int b = 0; b < 64; ++b) sum2[b][j] = acc[b];
      } else {
#pragma unroll
        for (int b = 0; b < 64; ++b) sum2[b][j] += acc[b];
      }
    }
    __syncthreads();
  }
  for (int idx = t; idx < 4096; idx += 256) {
    const int b = idx >> 6, jj = idx & 63;
    partial[(size_t)kc * 49152 + (size_t)b * D_IN + jc * 64 + jj] = sum2[b][jj];
  }
}

// ---------------- K5: out = sum(partials) + b2 -------------------------------
__global__ __launch_bounds__(256) void k5_final(const float* __restrict__ partial,
                                                const float* __restrict__ b2,
                                                float* __restrict__ out) {
  const int o = blockIdx.x * 256 + threadIdx.x;
  float v = b2[o % D_IN];
#pragma unroll
  for (int p = 0; p < 16; ++p) v += partial[(size_t)p * 49152 + o];
  out[o] = v;
}

extern "C" void kernel_launch(void* const* d_in, const int* in_sizes, int n_in,
                              void* d_out, int out_size, void* d_ws, size_t ws_size,
                              hipStream_t stream) {
  const float* X  = (const float*)d_in[0];
  const float* W1 = (const float*)d_in[1];
  const float* b1 = (const float*)d_in[2];
  const float* C  = (const float*)d_in[3];
  const float* W2 = (const float*)d_in[4];
  const float* b2 = (const float*)d_in[5];
  float* out = (float*)d_out;
  char* ws = (char*)d_ws;
  _Float16* W1T   = (_Float16*)ws;              //       0 .. 393,216
  float* pooled   = (float*)(ws + 393216);      // 393,216 .. 1,179,648
  float* stats    = (float*)(ws + 1179648);     // 1,179,648 .. 1,245,184
  _Float16* Ppart = (_Float16*)(ws + 1245184);  // 1,245,184 .. 13,828,096
  float* partial  = (float*)(ws + 1245184);     // aliases Ppart (used after KC)

  k0_w1t    <<<dim3(12, 4), 256, 0, stream>>>(W1, W1T);
  kf_fused  <<<2048,        512, 0, stream>>>(X, W1T, b1, C, Ppart, stats);
  kc_combine<<<64,          256, 0, stream>>>(Ppart, stats, pooled);
  k4_partial<<<dim3(12,16), 256, 0, stream>>>(pooled, W2, partial);
  k5_final  <<<192,         256, 0, stream>>>(partial, b2, out);
}

// Round 4
// 324.175 us; speedup vs baseline: 1.1270x; 1.0314x over previous
//
#include <hip/hip_runtime.h>

typedef _Float16 f16x8 __attribute__((ext_vector_type(8)));
typedef float f32x4 __attribute__((ext_vector_type(4)));

#define D_IN 768
#define D_H  256
#define SEQ  2048

// ---------------- K0: W1 [768][256] f32 -> W1T [256][768] f16 (transposed) ---
__global__ __launch_bounds__(256) void k0_w1t(const float* __restrict__ W1,
                                              _Float16* __restrict__ W1T) {
  __shared__ float tl[64][65];
  const int kb = blockIdx.x, nb = blockIdx.y, t = threadIdx.x;
#pragma unroll
  for (int rep = 0; rep < 16; ++rep) {
    const int row = rep * 4 + (t >> 6), col = t & 63;
    tl[row][col] = W1[(size_t)(kb * 64 + row) * D_H + nb * 64 + col];
  }
  __syncthreads();
#pragma unroll
  for (int rep = 0; rep < 16; ++rep) {
    const int n = rep * 4 + (t >> 6), k = t & 63;
    W1T[(size_t)(nb * 64 + n) * D_IN + kb * 64 + k] = (_Float16)tl[k][n];
  }
}

// ---------------- KF: fused logits + local softmax + local pooling -----------
// 4096 blocks (32 rows each) x 512 threads, 2 blocks/CU (54KB LDS, <=128 VGPR).
// Phase A: stage X tile to LDS barrier-free; ONE __syncthreads().
// Phase B: ZERO barriers. 8 waves, each owns a 32-col slice; B-fragments read
// directly from L2-resident W1T into registers. Waves free-run.
__global__ __launch_bounds__(512, 2) void kf_fused(const float* __restrict__ X,
    const _Float16* __restrict__ W1T, const float* __restrict__ b1,
    const float* __restrict__ C, _Float16* __restrict__ Ppart,
    float* __restrict__ stats) {
  __shared__ _Float16 Xl[32][776];     // 49,664 B (+8 pad)
  __shared__ float red2[8][32][4];     //  4,096 B per-wave logit partials
  __shared__ float red[32][4];         //    512 B
  const int t = threadIdx.x;
  const int bid = blockIdx.x;
  const size_t M0 = (size_t)bid * 32;

  // ---- phase A: stage X tile (32 x 768) f32 -> f16, no barriers ----
  const int xr = t >> 4, xk = (t & 15) * 8;     // row, k-base (6 steps of 128)
  const float* Ag = X + (M0 + xr) * D_IN + xk;
  float4 a[12];
#pragma unroll
  for (int s = 0; s < 6; ++s) {
    a[2 * s]     = *(const float4*)(Ag + s * 128);
    a[2 * s + 1] = *(const float4*)(Ag + s * 128 + 4);
  }
#pragma unroll
  for (int s = 0; s < 6; ++s) {
    f16x8 h;
    h[0] = (_Float16)a[2*s].x;   h[1] = (_Float16)a[2*s].y;
    h[2] = (_Float16)a[2*s].z;   h[3] = (_Float16)a[2*s].w;
    h[4] = (_Float16)a[2*s+1].x; h[5] = (_Float16)a[2*s+1].y;
    h[6] = (_Float16)a[2*s+1].z; h[7] = (_Float16)a[2*s+1].w;
    *(f16x8*)&Xl[xr][xk + s * 128] = h;
  }
  __syncthreads();   // the ONLY pre-epilogue barrier

  // ---- phase B: K-loop, barrier-free ----
  const int lane = t & 63, wn = t >> 6;         // 8 n-waves, cols wn*32..+31
  const int l15 = lane & 15, kg = lane >> 4;
  const _Float16* Bg0 = W1T + (size_t)(wn * 32 + l15) * D_IN + kg * 8;
  const _Float16* Bg1 = Bg0 + (size_t)16 * D_IN;

  f32x4 acc[2][2];
#pragma unroll
  for (int i = 0; i < 2; ++i)
#pragma unroll
    for (int j = 0; j < 2; ++j) acc[i][j] = f32x4{0.f, 0.f, 0.f, 0.f};

#pragma unroll
  for (int kt = 0; kt < 12; ++kt) {
    f16x8 bf[2][2], af[2][2];
#pragma unroll
    for (int st = 0; st < 2; ++st) {
      bf[0][st] = *(const f16x8*)(Bg0 + kt * 64 + st * 32);
      bf[1][st] = *(const f16x8*)(Bg1 + kt * 64 + st * 32);
      af[0][st] = *(const f16x8*)&Xl[l15][kt * 64 + st * 32 + kg * 8];
      af[1][st] = *(const f16x8*)&Xl[16 + l15][kt * 64 + st * 32 + kg * 8];
    }
#pragma unroll
    for (int st = 0; st < 2; ++st)
#pragma unroll
      for (int j = 0; j < 2; ++j)
#pragma unroll
        for (int i = 0; i < 2; ++i)
          acc[i][j] = __builtin_amdgcn_mfma_f32_16x16x32_f16(af[i][st], bf[j][st], acc[i][j], 0, 0, 0);
  }

  // ---- epilogue 1: z -> tanh -> project onto 4 context vectors ----
  float part[2][4][4];
#pragma unroll
  for (int i = 0; i < 2; ++i)
#pragma unroll
    for (int r = 0; r < 4; ++r)
#pragma unroll
      for (int c = 0; c < 4; ++c) part[i][r][c] = 0.f;

#pragma unroll
  for (int j = 0; j < 2; ++j) {
    const int col = wn * 32 + j * 16 + l15;
    const float4 c4 = *(const float4*)(C + col * 4);
    const float bv = b1[col];
#pragma unroll
    for (int i = 0; i < 2; ++i)
#pragma unroll
      for (int r = 0; r < 4; ++r) {
        float z = acc[i][j][r] + bv;
        z = fminf(fmaxf(z, -15.f), 15.f);
        const float e = __expf(2.f * z);
        const float h = (e - 1.f) / (e + 1.f);   // tanh(z)
        part[i][r][0] += h * c4.x;
        part[i][r][1] += h * c4.y;
        part[i][r][2] += h * c4.z;
        part[i][r][3] += h * c4.w;
      }
  }
#pragma unroll
  for (int off = 1; off < 16; off <<= 1) {
#pragma unroll
    for (int i = 0; i < 2; ++i)
#pragma unroll
      for (int r = 0; r < 4; ++r)
#pragma unroll
        for (int c = 0; c < 4; ++c)
          part[i][r][c] += __shfl_xor(part[i][r][c], off, 64);
  }
  if (l15 == 0) {   // lanes kg=0..3 hold row groups; plain writes, no atomics
#pragma unroll
    for (int i = 0; i < 2; ++i)
#pragma unroll
      for (int r = 0; r < 4; ++r)
#pragma unroll
        for (int c = 0; c < 4; ++c)
          red2[wn][i * 16 + kg * 4 + r][c] = part[i][r][c];
  }
  __syncthreads();

  // ---- epilogue 2: sum 8 wave-partials -> logits; local softmax ----
  if (t < 128) {
    const int r = t >> 2, c = t & 3;
    float v = 0.f;
#pragma unroll
    for (int w = 0; w < 8; ++w) v += red2[w][r][c];
    red[r][c] = v;
  }
  __syncthreads();
  if (t < 256) {
    const int c = t >> 6, r = t & 63;
    const float v = (r < 32) ? red[r][c] : -3.4e38f;
    float m = v;
#pragma unroll
    for (int off = 1; off < 64; off <<= 1) m = fmaxf(m, __shfl_xor(m, off, 64));
    const float e = (r < 32) ? __expf(v - m) : 0.f;
    if (r < 32) red[r][c] = e;
    float s = e;
#pragma unroll
    for (int off = 1; off < 64; off <<= 1) s += __shfl_xor(s, off, 64);
    if (r == 0) {
      stats[(size_t)bid * 8 + c * 2]     = m;
      stats[(size_t)bid * 8 + c * 2 + 1] = s;
    }
  }
  __syncthreads();

  // ---- epilogue 3: partial pooling P[c][d] = sum_r e[r][c] * Xl[r][d] ----
  const int pc = t >> 7, pch = t & 127;
  if (pch < 96) {
    float a8[8] = {0.f, 0.f, 0.f, 0.f, 0.f, 0.f, 0.f, 0.f};
#pragma unroll 4
    for (int r = 0; r < 32; ++r) {
      const float w = red[r][pc];
      const f16x8 x8 = *(const f16x8*)&Xl[r][pch * 8];
#pragma unroll
      for (int k = 0; k < 8; ++k) a8[k] += w * (float)x8[k];
    }
    f16x8 o;
#pragma unroll
    for (int k = 0; k < 8; ++k) o[k] = (_Float16)a8[k];
    *(f16x8*)&Ppart[(size_t)bid * 3072 + pc * 768 + pch * 8] = o;
  }
}

// ---------------- KC: combine 64 block-partials per batch -> pooled ----------
__global__ __launch_bounds__(256) void kc_combine(const _Float16* __restrict__ Ppart,
    const float* __restrict__ stats, float* __restrict__ pooled) {
  const int b = blockIdx.x, t = threadIdx.x;
  __shared__ float sm[64][8];
  __shared__ float Mc[4], Dc[4], fw[64][4];
  sm[t >> 2][(t & 3) * 2]     = stats[((size_t)b * 64 + (t >> 2)) * 8 + (t & 3) * 2];
  sm[t >> 2][(t & 3) * 2 + 1] = stats[((size_t)b * 64 + (t >> 2)) * 8 + (t & 3) * 2 + 1];
  __syncthreads();
  if (t < 4) {
    float m = sm[0][t * 2];
#pragma unroll 8
    for (int blk = 1; blk < 64; ++blk) m = fmaxf(m, sm[blk][t * 2]);
    Mc[t] = m;
  }
  __syncthreads();
  {
    const int blk = t >> 2, c = t & 3;
    fw[blk][c] = __expf(sm[blk][c * 2] - Mc[c]);
  }
  __syncthreads();
  if (t < 4) {
    float s = 0.f;
#pragma unroll 8
    for (int blk = 0; blk < 64; ++blk) s += fw[blk][t] * sm[blk][t * 2 + 1];
    Dc[t] = 1.f / s;
  }
  __syncthreads();
#pragma unroll
  for (int c = 0; c < 4; ++c) {
#pragma unroll
    for (int rep = 0; rep < 3; ++rep) {
      const int d = rep * 256 + t;
      float acc = 0.f;
#pragma unroll 8
      for (int blk = 0; blk < 64; ++blk)
        acc += fw[blk][c] * (float)Ppart[((size_t)(b * 64 + blk)) * 3072 + c * 768 + d];
      pooled[(size_t)b * 3072 + c * 768 + d] = fmaxf(acc * Dc[c], 0.f);
    }
  }
}

// ---------------- K4: partial[kc][b][j] = pooled(k-slice) @ W2(k-slice) ------
__global__ __launch_bounds__(256) void k4_partial(const float* __restrict__ pooled,
                                                  const float* __restrict__ W2,
                                                  float* __restrict__ partial) {
  const int jc = blockIdx.x, kc = blockIdx.y, t = threadIdx.x;
  __shared__ float plds[64 * 192];
  __shared__ float sum2[64][64];
  for (int idx = t; idx < 64 * 192; idx += 256) {
    const int b = idx / 192, k = idx - b * 192;
    plds[idx] = pooled[(size_t)b * 3072 + kc * 192 + k];
  }
  __syncthreads();
  const int j = t & 63, kp = t >> 6;
  float acc[64];
#pragma unroll
  for (int b = 0; b < 64; ++b) acc[b] = 0.f;
  const float* W2p = W2 + (size_t)(kc * 192 + kp * 48) * D_IN + jc * 64 + j;
  const float* pb = plds + kp * 48;
  for (int ki = 0; ki < 48; ki += 4) {
    const float w0 = W2p[(size_t)(ki + 0) * D_IN];
    const float w1 = W2p[(size_t)(ki + 1) * D_IN];
    const float w2 = W2p[(size_t)(ki + 2) * D_IN];
    const float w3 = W2p[(size_t)(ki + 3) * D_IN];
#pragma unroll
    for (int b = 0; b < 64; ++b) {
      const float4 p4 = *(const float4*)(pb + b * 192 + ki);
      acc[b] += p4.x * w0 + p4.y * w1 + p4.z * w2 + p4.w * w3;
    }
  }
#pragma unroll
  for (int p = 0; p < 4; ++p) {
    if (kp == p) {
      if (p == 0) {
#pragma unroll
        for (int b = 0; b < 64; ++b) sum2[b][j] = acc[b];
      } else {
#pragma unroll
        for (int b = 0; b < 64; ++b) sum2[b][j] += acc[b];
      }
    }
    __syncthreads();
  }
  for (int idx = t; idx < 4096; idx += 256) {
    const int b = idx >> 6, jj = idx & 63;
    partial[(size_t)kc * 49152 + (size_t)b * D_IN + jc * 64 + jj] = sum2[b][jj];
  }
}

// ---------------- K5: out = sum(partials) + b2 -------------------------------
__global__ __launch_bounds__(256) void k5_final(const float* __restrict__ partial,
                                                const float* __restrict__ b2,
                                                float* __restrict__ out) {
  const int o = blockIdx.x * 256 + threadIdx.x;
  float v = b2[o % D_IN];
#pragma unroll
  for (int p = 0; p < 16; ++p) v += partial[(size_t)p * 49152 + o];
  out[o] = v;
}

extern "C" void kernel_launch(void* const* d_in, const int* in_sizes, int n_in,
                              void* d_out, int out_size, void* d_ws, size_t ws_size,
                              hipStream_t stream) {
  const float* X  = (const float*)d_in[0];
  const float* W1 = (const float*)d_in[1];
  const float* b1 = (const float*)d_in[2];
  const float* C  = (const float*)d_in[3];
  const float* W2 = (const float*)d_in[4];
  const float* b2 = (const float*)d_in[5];
  float* out = (float*)d_out;
  char* ws = (char*)d_ws;
  _Float16* W1T   = (_Float16*)ws;              //         0 ..   393,216
  float* pooled   = (float*)(ws + 393216);      //   393,216 .. 1,179,648
  float* stats    = (float*)(ws + 1179648);     // 1,179,648 .. 1,310,720
  _Float16* Ppart = (_Float16*)(ws + 1310720);  // 1,310,720 .. 26,476,544
  float* partial  = (float*)(ws + 1310720);     // aliases Ppart (used after KC)

  k0_w1t    <<<dim3(12, 4), 256, 0, stream>>>(W1, W1T);
  kf_fused  <<<4096,        512, 0, stream>>>(X, W1T, b1, C, Ppart, stats);
  kc_combine<<<64,          256, 0, stream>>>(Ppart, stats, pooled);
  k4_partial<<<dim3(12,16), 256, 0, stream>>>(pooled, W2, partial);
  k5_final  <<<192,         256, 0, stream>>>(partial, b2, out);
}

// Round 5
// 307.515 us; speedup vs baseline: 1.1881x; 1.0542x over previous
//
#include <hip/hip_runtime.h>

typedef _Float16 f16x8 __attribute__((ext_vector_type(8)));
typedef _Float16 f16x4 __attribute__((ext_vector_type(4)));
typedef float f32x4 __attribute__((ext_vector_type(4)));

#define D_IN 768
#define D_H  256
#define SEQ  2048

// async global->LDS, 16B per lane; dest is wave-uniform-base + lane*16 (we pass
// base+lane*16 per-lane, which coincides with the hardware rule).
__device__ __forceinline__ void gld16(const void* g, void* l) {
  __builtin_amdgcn_global_load_lds(
      (const __attribute__((address_space(1))) unsigned int*)g,
      (__attribute__((address_space(3))) unsigned int*)l, 16, 0, 0);
}

// ---------------- K0: W1 [768][256] f32 -> W1T [256][768] f16 (transposed) ---
__global__ __launch_bounds__(256) void k0_w1t(const float* __restrict__ W1,
                                              _Float16* __restrict__ W1T) {
  __shared__ float tl[64][65];
  const int kb = blockIdx.x, nb = blockIdx.y, t = threadIdx.x;
#pragma unroll
  for (int rep = 0; rep < 16; ++rep) {
    const int row = rep * 4 + (t >> 6), col = t & 63;
    tl[row][col] = W1[(size_t)(kb * 64 + row) * D_H + nb * 64 + col];
  }
  __syncthreads();
#pragma unroll
  for (int rep = 0; rep < 16; ++rep) {
    const int n = rep * 4 + (t >> 6), k = t & 63;
    W1T[(size_t)(nb * 64 + n) * D_IN + kb * 64 + k] = (_Float16)tl[k][n];
  }
}

// ---------------- KF: fused logits + local softmax + local pooling -----------
// 2048 blocks (64 rows) x 256 threads, 27KB LDS + <=128 VGPR -> 4 blocks/CU.
// m97-style: global_load_lds staging (BK=32, single-buffered, 2 barriers/kt),
// XOR-swizzled sources+reads for conflict-free b128. Pool re-reads X from L3.
__global__ __launch_bounds__(256, 4) void kf_fused(const float* __restrict__ X,
    const _Float16* __restrict__ W1T, const float* __restrict__ b1,
    const float* __restrict__ C, _Float16* __restrict__ Ppart,
    float* __restrict__ stats) {
  __shared__ float    Al[64][32];      //  8KB, A tile f32, chunk = 16B = 4 f32
  __shared__ _Float16 Bl[256][32];     // 16KB, B tile f16, chunk = 16B = 8 f16
  __shared__ float    red2[2][64][4];  //  2KB
  __shared__ float    red[64][4];      //  1KB
  const int t = threadIdx.x;
  const int bid = blockIdx.x;
  const size_t M0 = (size_t)bid * 64;

  const int l = t & 63, w = t >> 6;
  // ---- staging geometry (lane l of wave w writes LDS base+l*16) ----
  // A: 8 x 1KB wave-chunks; chunk (w*2+q): rows (w*2+q)*8 + (l>>3), slot l&7.
  const int ar0 = (w * 2 + 0) * 8 + (l >> 3);
  const int ar1 = (w * 2 + 1) * 8 + (l >> 3);
  const int aj = l & 7;
  const float* As0 = X + (M0 + ar0) * D_IN + ((aj ^ (ar0 & 7)) * 4);
  const float* As1 = X + (M0 + ar1) * D_IN + ((aj ^ (ar1 & 7)) * 4);
  char* Ad0 = (char*)Al + (w * 2 + 0) * 1024 + l * 16;
  char* Ad1 = (char*)Al + (w * 2 + 1) * 1024 + l * 16;
  // B: 16 x 1KB wave-chunks; chunk (w*4+q): cols (w*4+q)*16 + (l>>2), slot l&3.
  const int bj = l & 3;
  const int bc0 = (w * 4 + 0) * 16 + (l >> 2);
  const int bc1 = (w * 4 + 1) * 16 + (l >> 2);
  const int bc2 = (w * 4 + 2) * 16 + (l >> 2);
  const int bc3 = (w * 4 + 3) * 16 + (l >> 2);
  const _Float16* Bs0 = W1T + (size_t)bc0 * D_IN + ((bj ^ (bc0 & 3)) * 8);
  const _Float16* Bs1 = W1T + (size_t)bc1 * D_IN + ((bj ^ (bc1 & 3)) * 8);
  const _Float16* Bs2 = W1T + (size_t)bc2 * D_IN + ((bj ^ (bc2 & 3)) * 8);
  const _Float16* Bs3 = W1T + (size_t)bc3 * D_IN + ((bj ^ (bc3 & 3)) * 8);
  char* Bd0 = (char*)Bl + (w * 4 + 0) * 1024 + l * 16;
  char* Bd1 = (char*)Bl + (w * 4 + 1) * 1024 + l * 16;
  char* Bd2 = (char*)Bl + (w * 4 + 2) * 1024 + l * 16;
  char* Bd3 = (char*)Bl + (w * 4 + 3) * 1024 + l * 16;

  // ---- compute geometry: 2 m-waves x 2 n-waves; wave = 32 rows x 128 cols ----
  const int wm = w >> 1, wn = w & 1;
  const int l15 = l & 15, kg = l >> 4;
  const int r0 = wm * 32 + l15, r1 = r0 + 16;
  const int sA0lo = ((2 * kg) ^ (r0 & 7)) * 4, sA0hi = ((2 * kg + 1) ^ (r0 & 7)) * 4;
  const int sA1lo = ((2 * kg) ^ (r1 & 7)) * 4, sA1hi = ((2 * kg + 1) ^ (r1 & 7)) * 4;

  f32x4 acc[2][8];
#pragma unroll
  for (int i = 0; i < 2; ++i)
#pragma unroll
    for (int n = 0; n < 8; ++n) acc[i][n] = f32x4{0.f, 0.f, 0.f, 0.f};

  for (int kt = 0; kt < 24; ++kt) {
    const int ko = kt * 32;   // f32 for A, f16 for B
    gld16(As0 + ko, Ad0);
    gld16(As1 + ko, Ad1);
    gld16(Bs0 + ko, Bd0);
    gld16(Bs1 + ko, Bd1);
    gld16(Bs2 + ko, Bd2);
    gld16(Bs3 + ko, Bd3);
    __syncthreads();   // drains the 6 loads; other 3 blocks/CU keep CU busy

    const float4 a0lo = *(const float4*)&Al[r0][sA0lo];
    const float4 a0hi = *(const float4*)&Al[r0][sA0hi];
    const float4 a1lo = *(const float4*)&Al[r1][sA1lo];
    const float4 a1hi = *(const float4*)&Al[r1][sA1hi];
    f16x8 af0, af1;
    af0[0] = (_Float16)a0lo.x; af0[1] = (_Float16)a0lo.y;
    af0[2] = (_Float16)a0lo.z; af0[3] = (_Float16)a0lo.w;
    af0[4] = (_Float16)a0hi.x; af0[5] = (_Float16)a0hi.y;
    af0[6] = (_Float16)a0hi.z; af0[7] = (_Float16)a0hi.w;
    af1[0] = (_Float16)a1lo.x; af1[1] = (_Float16)a1lo.y;
    af1[2] = (_Float16)a1lo.z; af1[3] = (_Float16)a1lo.w;
    af1[4] = (_Float16)a1hi.x; af1[5] = (_Float16)a1hi.y;
    af1[6] = (_Float16)a1hi.z; af1[7] = (_Float16)a1hi.w;
#pragma unroll
    for (int n = 0; n < 8; ++n) {
      const int col = wn * 128 + n * 16 + l15;
      const f16x8 bf = *(const f16x8*)&Bl[col][(kg ^ (col & 3)) * 8];
      acc[0][n] = __builtin_amdgcn_mfma_f32_16x16x32_f16(af0, bf, acc[0][n], 0, 0, 0);
      acc[1][n] = __builtin_amdgcn_mfma_f32_16x16x32_f16(af1, bf, acc[1][n], 0, 0, 0);
    }
    __syncthreads();   // tile consumed; safe to overwrite next kt
  }

  // ---- epilogue 1: z -> tanh -> project onto 4 context vectors ----
  float part[2][4][4];
#pragma unroll
  for (int i = 0; i < 2; ++i)
#pragma unroll
    for (int r = 0; r < 4; ++r)
#pragma unroll
      for (int c = 0; c < 4; ++c) part[i][r][c] = 0.f;

#pragma unroll
  for (int n = 0; n < 8; ++n) {
    const int col = wn * 128 + n * 16 + l15;
    const float4 c4 = *(const float4*)(C + col * 4);
    const float bv = b1[col];
#pragma unroll
    for (int i = 0; i < 2; ++i)
#pragma unroll
      for (int r = 0; r < 4; ++r) {
        float z = acc[i][n][r] + bv;
        z = fminf(fmaxf(z, -15.f), 15.f);
        const float e = __expf(2.f * z);
        const float h = (e - 1.f) / (e + 1.f);   // tanh(z)
        part[i][r][0] += h * c4.x;
        part[i][r][1] += h * c4.y;
        part[i][r][2] += h * c4.z;
        part[i][r][3] += h * c4.w;
      }
  }
#pragma unroll
  for (int off = 1; off < 16; off <<= 1) {
#pragma unroll
    for (int i = 0; i < 2; ++i)
#pragma unroll
      for (int r = 0; r < 4; ++r)
#pragma unroll
        for (int c = 0; c < 4; ++c)
          part[i][r][c] += __shfl_xor(part[i][r][c], off, 64);
  }
  if (l15 == 0) {
#pragma unroll
    for (int i = 0; i < 2; ++i)
#pragma unroll
      for (int r = 0; r < 4; ++r)
#pragma unroll
        for (int c = 0; c < 4; ++c)
          red2[wn][wm * 32 + i * 16 + kg * 4 + r][c] = part[i][r][c];
  }
  __syncthreads();

  // ---- epilogue 2: sum n-wave partials; block-local softmax (wave-parallel) --
  {
    const int r = t >> 2, c = t & 3;
    red[r][c] = red2[0][r][c] + red2[1][r][c];
  }
  __syncthreads();
  {
    const int c = t >> 6, r = t & 63;   // 4 waves, one per context
    const float v = red[r][c];
    float m = v;
#pragma unroll
    for (int off = 1; off < 64; off <<= 1) m = fmaxf(m, __shfl_xor(m, off, 64));
    const float e = __expf(v - m);
    red[r][c] = e;
    float s = e;
#pragma unroll
    for (int off = 1; off < 64; off <<= 1) s += __shfl_xor(s, off, 64);
    if (r == 0) {
      stats[(size_t)bid * 8 + c * 2]     = m;
      stats[(size_t)bid * 8 + c * 2 + 1] = s;
    }
  }
  __syncthreads();

  // ---- epilogue 3: pool from global X (L3-hot), f32 precision ----
  if (t < 192) {
    float pacc[4][4];
#pragma unroll
    for (int c = 0; c < 4; ++c)
#pragma unroll
      for (int j = 0; j < 4; ++j) pacc[c][j] = 0.f;
    const float* Xp = X + M0 * D_IN + t * 4;
#pragma unroll 4
    for (int r = 0; r < 64; ++r) {
      const float4 x4 = *(const float4*)(Xp + (size_t)r * D_IN);
      const float4 w4 = *(const float4*)&red[r][0];
      const float wc[4] = {w4.x, w4.y, w4.z, w4.w};
      const float xv[4] = {x4.x, x4.y, x4.z, x4.w};
#pragma unroll
      for (int c = 0; c < 4; ++c)
#pragma unroll
        for (int j = 0; j < 4; ++j) pacc[c][j] += wc[c] * xv[j];
    }
#pragma unroll
    for (int c = 0; c < 4; ++c) {
      f16x4 o;
#pragma unroll
      for (int j = 0; j < 4; ++j) o[j] = (_Float16)pacc[c][j];
      *(f16x4*)&Ppart[(size_t)bid * 3072 + c * 768 + t * 4] = o;
    }
  }
}

// ---------------- KC: combine 32 block-partials per batch -> pooled ----------
__global__ __launch_bounds__(256) void kc_combine(const _Float16* __restrict__ Ppart,
    const float* __restrict__ stats, float* __restrict__ pooled) {
  const int b = blockIdx.x, t = threadIdx.x;
  __shared__ float sm[32][8];
  __shared__ float Mc[4], Dc[4], fw[32][4];
  sm[t >> 3][t & 7] = stats[((size_t)b * 32 + (t >> 3)) * 8 + (t & 7)];
  __syncthreads();
  if (t < 4) {
    float m = sm[0][t * 2];
#pragma unroll
    for (int blk = 1; blk < 32; ++blk) m = fmaxf(m, sm[blk][t * 2]);
    Mc[t] = m;
  }
  __syncthreads();
  if (t < 128) {
    const int blk = t >> 2, c = t & 3;
    fw[blk][c] = __expf(sm[blk][c * 2] - Mc[c]);
  }
  __syncthreads();
  if (t < 4) {
    float s = 0.f;
#pragma unroll
    for (int blk = 0; blk < 32; ++blk) s += fw[blk][t] * sm[blk][t * 2 + 1];
    Dc[t] = 1.f / s;
  }
  __syncthreads();
#pragma unroll
  for (int c = 0; c < 4; ++c) {
#pragma unroll
    for (int rep = 0; rep < 3; ++rep) {
      const int d = rep * 256 + t;
      float acc = 0.f;
#pragma unroll 4
      for (int blk = 0; blk < 32; ++blk)
        acc += fw[blk][c] * (float)Ppart[((size_t)(b * 32 + blk)) * 3072 + c * 768 + d];
      pooled[(size_t)b * 3072 + c * 768 + d] = fmaxf(acc * Dc[c], 0.f);
    }
  }
}

// ---------------- K4: partial[kc][b][j] = pooled(k-slice) @ W2(k-slice) ------
__global__ __launch_bounds__(256) void k4_partial(const float* __restrict__ pooled,
                                                  const float* __restrict__ W2,
                                                  float* __restrict__ partial) {
  const int jc = blockIdx.x, kc = blockIdx.y, t = threadIdx.x;
  __shared__ float plds[64 * 192];
  __shared__ float sum2[64][64];
  for (int idx = t; idx < 64 * 192; idx += 256) {
    const int b = idx / 192, k = idx - b * 192;
    plds[idx] = pooled[(size_t)b * 3072 + kc * 192 + k];
  }
  __syncthreads();
  const int j = t & 63, kp = t >> 6;
  float acc[64];
#pragma unroll
  for (int b = 0; b < 64; ++b) acc[b] = 0.f;
  const float* W2p = W2 + (size_t)(kc * 192 + kp * 48) * D_IN + jc * 64 + j;
  const float* pb = plds + kp * 48;
  for (int ki = 0; ki < 48; ki += 4) {
    const float w0 = W2p[(size_t)(ki + 0) * D_IN];
    const float w1 = W2p[(size_t)(ki + 1) * D_IN];
    const float w2 = W2p[(size_t)(ki + 2) * D_IN];
    const float w3 = W2p[(size_t)(ki + 3) * D_IN];
#pragma unroll
    for (int b = 0; b < 64; ++b) {
      const float4 p4 = *(const float4*)(pb + b * 192 + ki);
      acc[b] += p4.x * w0 + p4.y * w1 + p4.z * w2 + p4.w * w3;
    }
  }
#pragma unroll
  for (int p = 0; p < 4; ++p) {
    if (kp == p) {
      if (p == 0) {
#pragma unroll
        for (int b = 0; b < 64; ++b) sum2[b][j] = acc[b];
      } else {
#pragma unroll
        for (int b = 0; b < 64; ++b) sum2[b][j] += acc[b];
      }
    }
    __syncthreads();
  }
  for (int idx = t; idx < 4096; idx += 256) {
    const int b = idx >> 6, jj = idx & 63;
    partial[(size_t)kc * 49152 + (size_t)b * D_IN + jc * 64 + jj] = sum2[b][jj];
  }
}

// ---------------- K5: out = sum(partials) + b2 -------------------------------
__global__ __launch_bounds__(256) void k5_final(const float* __restrict__ partial,
                                                const float* __restrict__ b2,
                                                float* __restrict__ out) {
  const int o = blockIdx.x * 256 + threadIdx.x;
  float v = b2[o % D_IN];
#pragma unroll
  for (int p = 0; p < 16; ++p) v += partial[(size_t)p * 49152 + o];
  out[o] = v;
}

extern "C" void kernel_launch(void* const* d_in, const int* in_sizes, int n_in,
                              void* d_out, int out_size, void* d_ws, size_t ws_size,
                              hipStream_t stream) {
  const float* X  = (const float*)d_in[0];
  const float* W1 = (const float*)d_in[1];
  const float* b1 = (const float*)d_in[2];
  const float* C  = (const float*)d_in[3];
  const float* W2 = (const float*)d_in[4];
  const float* b2 = (const float*)d_in[5];
  float* out = (float*)d_out;
  char* ws = (char*)d_ws;
  _Float16* W1T   = (_Float16*)ws;              //         0 ..   393,216
  float* pooled   = (float*)(ws + 393216);      //   393,216 .. 1,179,648
  float* stats    = (float*)(ws + 1179648);     // 1,179,648 .. 1,245,184
  _Float16* Ppart = (_Float16*)(ws + 1245184);  // 1,245,184 .. 13,828,096
  float* partial  = (float*)(ws + 1245184);     // aliases Ppart (used after KC)

  k0_w1t    <<<dim3(12, 4), 256, 0, stream>>>(W1, W1T);
  kf_fused  <<<2048,        256, 0, stream>>>(X, W1T, b1, C, Ppart, stats);
  kc_combine<<<64,          256, 0, stream>>>(Ppart, stats, pooled);
  k4_partial<<<dim3(12,16), 256, 0, stream>>>(pooled, W2, partial);
  k5_final  <<<192,         256, 0, stream>>>(partial, b2, out);
}

// Round 6
// 279.731 us; speedup vs baseline: 1.3061x; 1.0993x over previous
//
#include <hip/hip_runtime.h>

typedef _Float16 f16x8 __attribute__((ext_vector_type(8)));
typedef _Float16 f16x4 __attribute__((ext_vector_type(4)));
typedef float f32x4 __attribute__((ext_vector_type(4)));

#define D_IN 768
#define D_H  256
#define SEQ  2048

// async global->LDS, 16B per lane (dest = wave-uniform base + lane*16).
__device__ __forceinline__ void gld16(const void* g, void* l) {
  __builtin_amdgcn_global_load_lds(
      (const __attribute__((address_space(1))) unsigned int*)g,
      (__attribute__((address_space(3))) unsigned int*)l, 16, 0, 0);
}

// ---------------- K0: W1 [768][256] f32 -> W1T [256][768] f16 (transposed) ---
__global__ __launch_bounds__(256) void k0_w1t(const float* __restrict__ W1,
                                              _Float16* __restrict__ W1T) {
  __shared__ float tl[64][65];
  const int kb = blockIdx.x, nb = blockIdx.y, t = threadIdx.x;
#pragma unroll
  for (int rep = 0; rep < 16; ++rep) {
    const int row = rep * 4 + (t >> 6), col = t & 63;
    tl[row][col] = W1[(size_t)(kb * 64 + row) * D_H + nb * 64 + col];
  }
  __syncthreads();
#pragma unroll
  for (int rep = 0; rep < 16; ++rep) {
    const int n = rep * 4 + (t >> 6), k = t & 63;
    W1T[(size_t)(nb * 64 + n) * D_IN + kb * 64 + k] = (_Float16)tl[k][n];
  }
}

// ---------------- KF: fused logits + local softmax + local pooling -----------
// 2048 blocks (64 rows) x 256 threads, 51KB LDS -> 3 blocks/CU.
// Double-buffered gld_lds staging, RAW s_barrier + counted vmcnt(6):
// next tile's 6 loads stay in flight across both barriers (T3/T4, m201).
__global__ __launch_bounds__(256, 3) void kf_fused(const float* __restrict__ X,
    const _Float16* __restrict__ W1T, const float* __restrict__ b1,
    const float* __restrict__ C, _Float16* __restrict__ Ppart,
    float* __restrict__ stats) {
  __shared__ float    Al[2][64][32];   // 16KB, A tiles f32 (chunk = 16B = 4 f32)
  __shared__ _Float16 Bl[2][256][32];  // 32KB, B tiles f16 (chunk = 16B = 8 f16)
  __shared__ float    red2[2][64][4];  //  2KB
  __shared__ float    red[64][4];      //  1KB
  const int t = threadIdx.x;
  const int bid = blockIdx.x;
  const size_t M0 = (size_t)bid * 64;

  const int l = t & 63, w = t >> 6;
  // ---- staging geometry (lane l of wave w writes LDS chunkbase + l*16) ----
  const int ar0 = (w * 2 + 0) * 8 + (l >> 3);
  const int ar1 = (w * 2 + 1) * 8 + (l >> 3);
  const int aj = l & 7;
  const float* As0 = X + (M0 + ar0) * D_IN + ((aj ^ (ar0 & 7)) * 4);
  const float* As1 = X + (M0 + ar1) * D_IN + ((aj ^ (ar1 & 7)) * 4);
  const int ad0 = (w * 2 + 0) * 1024 + l * 16;
  const int ad1 = (w * 2 + 1) * 1024 + l * 16;
  const int bj = l & 3;
  const int bc0 = (w * 4 + 0) * 16 + (l >> 2);
  const int bc1 = (w * 4 + 1) * 16 + (l >> 2);
  const int bc2 = (w * 4 + 2) * 16 + (l >> 2);
  const int bc3 = (w * 4 + 3) * 16 + (l >> 2);
  const _Float16* Bs0 = W1T + (size_t)bc0 * D_IN + ((bj ^ (bc0 & 3)) * 8);
  const _Float16* Bs1 = W1T + (size_t)bc1 * D_IN + ((bj ^ (bc1 & 3)) * 8);
  const _Float16* Bs2 = W1T + (size_t)bc2 * D_IN + ((bj ^ (bc2 & 3)) * 8);
  const _Float16* Bs3 = W1T + (size_t)bc3 * D_IN + ((bj ^ (bc3 & 3)) * 8);
  const int bd0 = (w * 4 + 0) * 1024 + l * 16;
  const int bd1 = (w * 4 + 1) * 1024 + l * 16;
  const int bd2 = (w * 4 + 2) * 1024 + l * 16;
  const int bd3 = (w * 4 + 3) * 1024 + l * 16;

  // ---- compute geometry: 2 m-waves x 2 n-waves; wave = 32 rows x 128 cols ---
  const int wm = w >> 1, wn = w & 1;
  const int l15 = l & 15, kg = l >> 4;
  const int r0 = wm * 32 + l15, r1 = r0 + 16;
  const int sA0lo = ((2 * kg) ^ (r0 & 7)) * 4, sA0hi = ((2 * kg + 1) ^ (r0 & 7)) * 4;
  const int sA1lo = ((2 * kg) ^ (r1 & 7)) * 4, sA1hi = ((2 * kg + 1) ^ (r1 & 7)) * 4;

  f32x4 acc[2][8];
#pragma unroll
  for (int i = 0; i < 2; ++i)
#pragma unroll
    for (int n = 0; n < 8; ++n) acc[i][n] = f32x4{0.f, 0.f, 0.f, 0.f};

  auto issue6 = [&](int kt, int bsel) {
    const int ko = kt * 32;
    char* ab = (char*)&Al[bsel][0][0];
    char* bb = (char*)&Bl[bsel][0][0];
    gld16(As0 + ko, ab + ad0);
    gld16(As1 + ko, ab + ad1);
    gld16(Bs0 + ko, bb + bd0);
    gld16(Bs1 + ko, bb + bd1);
    gld16(Bs2 + ko, bb + bd2);
    gld16(Bs3 + ko, bb + bd3);
  };

  auto compute = [&](int bsel) {
    const float4 a0lo = *(const float4*)&Al[bsel][r0][sA0lo];
    const float4 a0hi = *(const float4*)&Al[bsel][r0][sA0hi];
    const float4 a1lo = *(const float4*)&Al[bsel][r1][sA1lo];
    const float4 a1hi = *(const float4*)&Al[bsel][r1][sA1hi];
    f16x8 af0, af1;
    af0[0] = (_Float16)a0lo.x; af0[1] = (_Float16)a0lo.y;
    af0[2] = (_Float16)a0lo.z; af0[3] = (_Float16)a0lo.w;
    af0[4] = (_Float16)a0hi.x; af0[5] = (_Float16)a0hi.y;
    af0[6] = (_Float16)a0hi.z; af0[7] = (_Float16)a0hi.w;
    af1[0] = (_Float16)a1lo.x; af1[1] = (_Float16)a1lo.y;
    af1[2] = (_Float16)a1lo.z; af1[3] = (_Float16)a1lo.w;
    af1[4] = (_Float16)a1hi.x; af1[5] = (_Float16)a1hi.y;
    af1[6] = (_Float16)a1hi.z; af1[7] = (_Float16)a1hi.w;
#pragma unroll
    for (int n = 0; n < 8; ++n) {
      const int col = wn * 128 + n * 16 + l15;
      const f16x8 bf = *(const f16x8*)&Bl[bsel][col][(kg ^ (col & 3)) * 8];
      acc[0][n] = __builtin_amdgcn_mfma_f32_16x16x32_f16(af0, bf, acc[0][n], 0, 0, 0);
      acc[1][n] = __builtin_amdgcn_mfma_f32_16x16x32_f16(af1, bf, acc[1][n], 0, 0, 0);
    }
  };

  // prologue: tiles 0 and 1 in flight (12 loads/thread)
  issue6(0, 0);
  issue6(1, 1);

  // main: kt = 0..21; tile kt+1 stays in flight across both barriers
  for (int kp = 0; kp < 11; ++kp) {
#pragma unroll
    for (int par = 0; par < 2; ++par) {
      const int kt = 2 * kp + par;
      asm volatile("s_waitcnt vmcnt(6)" ::: "memory");   // tile kt landed
      __builtin_amdgcn_sched_barrier(0);
      __builtin_amdgcn_s_barrier();
      compute(par);
      __builtin_amdgcn_sched_barrier(0);
      __builtin_amdgcn_s_barrier();                      // buf[par] free
      if (kt < 22) issue6(kt + 2, par);
      __builtin_amdgcn_sched_barrier(0);
    }
  }
  // peel kt = 22 (tile 23 still in flight), kt = 23 (drain)
  asm volatile("s_waitcnt vmcnt(6)" ::: "memory");
  __builtin_amdgcn_sched_barrier(0);
  __builtin_amdgcn_s_barrier();
  compute(0);
  __builtin_amdgcn_sched_barrier(0);
  __builtin_amdgcn_s_barrier();
  asm volatile("s_waitcnt vmcnt(0)" ::: "memory");
  __builtin_amdgcn_sched_barrier(0);
  __builtin_amdgcn_s_barrier();
  compute(1);

  // ---- epilogue 1: z -> tanh -> project onto 4 context vectors ----
  float part[2][4][4];
#pragma unroll
  for (int i = 0; i < 2; ++i)
#pragma unroll
    for (int r = 0; r < 4; ++r)
#pragma unroll
      for (int c = 0; c < 4; ++c) part[i][r][c] = 0.f;

#pragma unroll
  for (int n = 0; n < 8; ++n) {
    const int col = wn * 128 + n * 16 + l15;
    const float4 c4 = *(const float4*)(C + col * 4);
    const float bv = b1[col];
#pragma unroll
    for (int i = 0; i < 2; ++i)
#pragma unroll
      for (int r = 0; r < 4; ++r) {
        float z = acc[i][n][r] + bv;
        z = fminf(fmaxf(z, -15.f), 15.f);
        const float e = __expf(2.f * z);
        const float h = (e - 1.f) / (e + 1.f);   // tanh(z)
        part[i][r][0] += h * c4.x;
        part[i][r][1] += h * c4.y;
        part[i][r][2] += h * c4.z;
        part[i][r][3] += h * c4.w;
      }
  }
#pragma unroll
  for (int off = 1; off < 16; off <<= 1) {
#pragma unroll
    for (int i = 0; i < 2; ++i)
#pragma unroll
      for (int r = 0; r < 4; ++r)
#pragma unroll
        for (int c = 0; c < 4; ++c)
          part[i][r][c] += __shfl_xor(part[i][r][c], off, 64);
  }
  if (l15 == 0) {
#pragma unroll
    for (int i = 0; i < 2; ++i)
#pragma unroll
      for (int r = 0; r < 4; ++r)
#pragma unroll
        for (int c = 0; c < 4; ++c)
          red2[wn][wm * 32 + i * 16 + kg * 4 + r][c] = part[i][r][c];
  }
  __syncthreads();

  // ---- epilogue 2: sum n-wave partials; block-local softmax (wave-parallel) --
  {
    const int r = t >> 2, c = t & 3;
    red[r][c] = red2[0][r][c] + red2[1][r][c];
  }
  __syncthreads();
  {
    const int c = t >> 6, r = t & 63;   // 4 waves, one per context
    const float v = red[r][c];
    float m = v;
#pragma unroll
    for (int off = 1; off < 64; off <<= 1) m = fmaxf(m, __shfl_xor(m, off, 64));
    const float e = __expf(v - m);
    red[r][c] = e;
    float s = e;
#pragma unroll
    for (int off = 1; off < 64; off <<= 1) s += __shfl_xor(s, off, 64);
    if (r == 0) {
      stats[(size_t)bid * 8 + c * 2]     = m;
      stats[(size_t)bid * 8 + c * 2 + 1] = s;
    }
  }
  __syncthreads();

  // ---- epilogue 3: pool from global X (L2/L3-hot), f32 precision ----
  if (t < 192) {
    float pacc[4][4];
#pragma unroll
    for (int c = 0; c < 4; ++c)
#pragma unroll
      for (int j = 0; j < 4; ++j) pacc[c][j] = 0.f;
    const float* Xp = X + M0 * D_IN + t * 4;
#pragma unroll 8
    for (int r = 0; r < 64; ++r) {
      const float4 x4 = *(const float4*)(Xp + (size_t)r * D_IN);
      const float4 w4 = *(const float4*)&red[r][0];
      const float wc[4] = {w4.x, w4.y, w4.z, w4.w};
      const float xv[4] = {x4.x, x4.y, x4.z, x4.w};
#pragma unroll
      for (int c = 0; c < 4; ++c)
#pragma unroll
        for (int j = 0; j < 4; ++j) pacc[c][j] += wc[c] * xv[j];
    }
#pragma unroll
    for (int c = 0; c < 4; ++c) {
      f16x4 o;
#pragma unroll
      for (int j = 0; j < 4; ++j) o[j] = (_Float16)pacc[c][j];
      *(f16x4*)&Ppart[(size_t)bid * 3072 + c * 768 + t * 4] = o;
    }
  }
}

// ---------------- KC: combine 32 block-partials per batch -> pooled ----------
__global__ __launch_bounds__(256) void kc_combine(const _Float16* __restrict__ Ppart,
    const float* __restrict__ stats, float* __restrict__ pooled) {
  const int b = blockIdx.x, t = threadIdx.x;
  __shared__ float sm[32][8];
  __shared__ float Mc[4], Dc[4], fw[32][4];
  sm[t >> 3][t & 7] = stats[((size_t)b * 32 + (t >> 3)) * 8 + (t & 7)];
  __syncthreads();
  if (t < 4) {
    float m = sm[0][t * 2];
#pragma unroll
    for (int blk = 1; blk < 32; ++blk) m = fmaxf(m, sm[blk][t * 2]);
    Mc[t] = m;
  }
  __syncthreads();
  if (t < 128) {
    const int blk = t >> 2, c = t & 3;
    fw[blk][c] = __expf(sm[blk][c * 2] - Mc[c]);
  }
  __syncthreads();
  if (t < 4) {
    float s = 0.f;
#pragma unroll
    for (int blk = 0; blk < 32; ++blk) s += fw[blk][t] * sm[blk][t * 2 + 1];
    Dc[t] = 1.f / s;
  }
  __syncthreads();
#pragma unroll
  for (int c = 0; c < 4; ++c) {
#pragma unroll
    for (int rep = 0; rep < 3; ++rep) {
      const int d = rep * 256 + t;
      float acc = 0.f;
#pragma unroll 4
      for (int blk = 0; blk < 32; ++blk)
        acc += fw[blk][c] * (float)Ppart[((size_t)(b * 32 + blk)) * 3072 + c * 768 + d];
      pooled[(size_t)b * 3072 + c * 768 + d] = fmaxf(acc * Dc[c], 0.f);
    }
  }
}

// ---------------- K4: partial[kc][b][j] = pooled(k-slice) @ W2(k-slice) ------
__global__ __launch_bounds__(256) void k4_partial(const float* __restrict__ pooled,
                                                  const float* __restrict__ W2,
                                                  float* __restrict__ partial) {
  const int jc = blockIdx.x, kc = blockIdx.y, t = threadIdx.x;
  __shared__ float plds[64 * 192];
  __shared__ float sum2[64][64];
  for (int idx = t; idx < 64 * 192; idx += 256) {
    const int b = idx / 192, k = idx - b * 192;
    plds[idx] = pooled[(size_t)b * 3072 + kc * 192 + k];
  }
  __syncthreads();
  const int j = t & 63, kp = t >> 6;
  float acc[64];
#pragma unroll
  for (int b = 0; b < 64; ++b) acc[b] = 0.f;
  const float* W2p = W2 + (size_t)(kc * 192 + kp * 48) * D_IN + jc * 64 + j;
  const float* pb = plds + kp * 48;
  for (int ki = 0; ki < 48; ki += 4) {
    const float w0 = W2p[(size_t)(ki + 0) * D_IN];
    const float w1 = W2p[(size_t)(ki + 1) * D_IN];
    const float w2 = W2p[(size_t)(ki + 2) * D_IN];
    const float w3 = W2p[(size_t)(ki + 3) * D_IN];
#pragma unroll
    for (int b = 0; b < 64; ++b) {
      const float4 p4 = *(const float4*)(pb + b * 192 + ki);
      acc[b] += p4.x * w0 + p4.y * w1 + p4.z * w2 + p4.w * w3;
    }
  }
#pragma unroll
  for (int p = 0; p < 4; ++p) {
    if (kp == p) {
      if (p == 0) {
#pragma unroll
        for (int b = 0; b < 64; ++b) sum2[b][j] = acc[b];
      } else {
#pragma unroll
        for (int b = 0; b < 64; ++b) sum2[b][j] += acc[b];
      }
    }
    __syncthreads();
  }
  for (int idx = t; idx < 4096; idx += 256) {
    const int b = idx >> 6, jj = idx & 63;
    partial[(size_t)kc * 49152 + (size_t)b * D_IN + jc * 64 + jj] = sum2[b][jj];
  }
}

// ---------------- K5: out = sum(partials) + b2 -------------------------------
__global__ __launch_bounds__(256) void k5_final(const float* __restrict__ partial,
                                                const float* __restrict__ b2,
                                                float* __restrict__ out) {
  const int o = blockIdx.x * 256 + threadIdx.x;
  float v = b2[o % D_IN];
#pragma unroll
  for (int p = 0; p < 16; ++p) v += partial[(size_t)p * 49152 + o];
  out[o] = v;
}

extern "C" void kernel_launch(void* const* d_in, const int* in_sizes, int n_in,
                              void* d_out, int out_size, void* d_ws, size_t ws_size,
                              hipStream_t stream) {
  const float* X  = (const float*)d_in[0];
  const float* W1 = (const float*)d_in[1];
  const float* b1 = (const float*)d_in[2];
  const float* C  = (const float*)d_in[3];
  const float* W2 = (const float*)d_in[4];
  const float* b2 = (const float*)d_in[5];
  float* out = (float*)d_out;
  char* ws = (char*)d_ws;
  _Float16* W1T   = (_Float16*)ws;              //         0 ..   393,216
  float* pooled   = (float*)(ws + 393216);      //   393,216 .. 1,179,648
  float* stats    = (float*)(ws + 1179648);     // 1,179,648 .. 1,245,184
  _Float16* Ppart = (_Float16*)(ws + 1245184);  // 1,245,184 .. 13,828,096
  float* partial  = (float*)(ws + 1245184);     // aliases Ppart (used after KC)

  k0_w1t    <<<dim3(12, 4), 256, 0, stream>>>(W1, W1T);
  kf_fused  <<<2048,        256, 0, stream>>>(X, W1T, b1, C, Ppart, stats);
  kc_combine<<<64,          256, 0, stream>>>(Ppart, stats, pooled);
  k4_partial<<<dim3(12,16), 256, 0, stream>>>(pooled, W2, partial);
  k5_final  <<<192,         256, 0, stream>>>(partial, b2, out);
}